// Round 6
// baseline (49.974 us; speedup 1.0000x reference)
//
#include <hip/hip_runtime.h>
#include <stdint.h>

#define KDIM 2048
#define NEXP 64
#define MT   32              // tokens per block
#define KC   64              // k per chunk (two MFMA k-steps)
#define NCH  (KDIM / KC)     // 32 chunks
#define NTHR 256             // 4 waves

typedef _Float16 half8 __attribute__((ext_vector_type(8)));
typedef __fp16  fp16x2 __attribute__((ext_vector_type(2)));
typedef float f32x4 __attribute__((ext_vector_type(4)));

// W[64][2048] f32 -> Wh/Wl [64][2048] f16 (scaled by 256, hi/lo split)
__global__ __launch_bounds__(256) void prep_w(const float* __restrict__ W,
                                              _Float16* __restrict__ Wh,
                                              _Float16* __restrict__ Wl) {
    int idx = blockIdx.x * 256 + threadIdx.x;   // 131072 total
    float y = W[idx] * 256.0f;
    _Float16 h = (_Float16)y;
    _Float16 l = (_Float16)(y - (float)h);
    Wh[idx] = h;
    Wl[idx] = l;
}

// swizzled byte offset within one [rows][128 B] LDS tensor
__device__ __forceinline__ int swz(int row, int byte_in_row) {
    return (row << 7) + (byte_in_row ^ ((row & 7) << 4));
}

__device__ __forceinline__ uint32_t pkrtz(float a, float b) {
    fp16x2 h = __builtin_amdgcn_cvt_pkrtz(a, b);
    return __builtin_bit_cast(uint32_t, h);
}
__device__ __forceinline__ float lo_f(uint32_t u) {
    fp16x2 h = __builtin_bit_cast(fp16x2, u);
    return (float)h[0];
}
__device__ __forceinline__ float hi_f(uint32_t u) {
    fp16x2 h = __builtin_bit_cast(fp16x2, u);
    return (float)h[1];
}

__global__ __launch_bounds__(NTHR) void router_kernel(const float* __restrict__ x,
                                                      const _Float16* __restrict__ Wh,
                                                      const _Float16* __restrict__ Wl,
                                                      float* __restrict__ out_w,
                                                      float* __restrict__ out_i) {
    __shared__ char AhB[2][4096];      // 32 tok x 64 k f16 (hi), swizzled
    __shared__ char AlB[2][4096];      // (lo)
    __shared__ char BhB[2][8192];      // 64 exp x 64 k f16 (hi)
    __shared__ char BlB[2][8192];      // (lo)              -> 48 KB
    __shared__ float ss[MT][NEXP + 3]; // scores, odd-ish stride   8.4 KB

    const int tid  = threadIdx.x;
    const int lane = tid & 63;
    const int wave = tid >> 6;
    const int wm   = wave >> 1;        // token half (16 tok)
    const int wn   = wave & 1;         // expert half (32 exp)
    const int tb   = blockIdx.x * MT;

    // ---- staging coords ----
    // x: thread t reads 8 consecutive f32: row = t>>3, col8 = t&7 (256 B/row chunk)
    const int trow = tid >> 3;
    const int tc8  = tid & 7;
    const float* xsrc = x + (size_t)(tb + trow) * KDIM + tc8 * 8;
    const int xoff = swz(trow, tc8 * 16);
    // W: thread t reads 16 consecutive f16: row = t>>2, col = (t&3)*16 (128 B/row chunk)
    const int wrow = tid >> 2;
    const int wc   = tid & 3;
    const _Float16* whs = Wh + (size_t)wrow * KDIM + wc * 16;
    const _Float16* wls = Wl + (size_t)wrow * KDIM + wc * 16;
    const int woff0 = swz(wrow, wc * 32);
    const int woff1 = swz(wrow, wc * 32 + 16);

    // ---- compute-side read offsets (A and B share the lane->k mapping) ----
    int aoff[2], boff0[2], boff1[2];
    #pragma unroll
    for (int ks = 0; ks < 2; ++ks) {
        const int byt = ks * 64 + (lane >> 4) * 16;
        aoff[ks]  = swz(wm * 16 + (lane & 15), byt);
        boff0[ks] = swz(wn * 32 +      (lane & 15), byt);
        boff1[ks] = swz(wn * 32 + 16 + (lane & 15), byt);
    }

    f32x4 acc[2];
    acc[0] = (f32x4){0.f, 0.f, 0.f, 0.f};
    acc[1] = (f32x4){0.f, 0.f, 0.f, 0.f};

    float4 rx0, rx1;
    half8  rwh0, rwh1, rwl0, rwl1;

    auto LOAD = [&](int c) {
        const float4* xs4 = reinterpret_cast<const float4*>(xsrc + c * KC);
        rx0 = xs4[0];
        rx1 = xs4[1];
        rwh0 = *reinterpret_cast<const half8*>(whs + c * KC);
        rwh1 = *reinterpret_cast<const half8*>(whs + c * KC + 8);
        rwl0 = *reinterpret_cast<const half8*>(wls + c * KC);
        rwl1 = *reinterpret_cast<const half8*>(wls + c * KC + 8);
    };

    auto STORE = [&](int b) {
        float yv[8] = {rx0.x, rx0.y, rx0.z, rx0.w, rx1.x, rx1.y, rx1.z, rx1.w};
        uint4 hv, lv;
        uint32_t h[4], l[4];
        #pragma unroll
        for (int i = 0; i < 4; ++i) {
            float a = yv[2 * i] * 256.0f;
            float b2 = yv[2 * i + 1] * 256.0f;
            h[i] = pkrtz(a, b2);
            l[i] = pkrtz(a - lo_f(h[i]), b2 - hi_f(h[i]));
        }
        hv.x = h[0]; hv.y = h[1]; hv.z = h[2]; hv.w = h[3];
        lv.x = l[0]; lv.y = l[1]; lv.z = l[2]; lv.w = l[3];
        *reinterpret_cast<uint4*>(&AhB[b][0] + xoff) = hv;
        *reinterpret_cast<uint4*>(&AlB[b][0] + xoff) = lv;
        *reinterpret_cast<half8*>(&BhB[b][0] + woff0) = rwh0;
        *reinterpret_cast<half8*>(&BhB[b][0] + woff1) = rwh1;
        *reinterpret_cast<half8*>(&BlB[b][0] + woff0) = rwl0;
        *reinterpret_cast<half8*>(&BlB[b][0] + woff1) = rwl1;
    };

    auto COMPUTE = [&](int b) {
        #pragma unroll
        for (int ks = 0; ks < 2; ++ks) {
            half8 a_h = *reinterpret_cast<const half8*>(&AhB[b][0] + aoff[ks]);
            half8 a_l = *reinterpret_cast<const half8*>(&AlB[b][0] + aoff[ks]);
            half8 b_h0 = *reinterpret_cast<const half8*>(&BhB[b][0] + boff0[ks]);
            half8 b_h1 = *reinterpret_cast<const half8*>(&BhB[b][0] + boff1[ks]);
            half8 b_l0 = *reinterpret_cast<const half8*>(&BlB[b][0] + boff0[ks]);
            half8 b_l1 = *reinterpret_cast<const half8*>(&BlB[b][0] + boff1[ks]);
            acc[0] = __builtin_amdgcn_mfma_f32_16x16x32_f16(a_h, b_h0, acc[0], 0, 0, 0);
            acc[0] = __builtin_amdgcn_mfma_f32_16x16x32_f16(a_l, b_h0, acc[0], 0, 0, 0);
            acc[0] = __builtin_amdgcn_mfma_f32_16x16x32_f16(a_h, b_l0, acc[0], 0, 0, 0);
            acc[1] = __builtin_amdgcn_mfma_f32_16x16x32_f16(a_h, b_h1, acc[1], 0, 0, 0);
            acc[1] = __builtin_amdgcn_mfma_f32_16x16x32_f16(a_l, b_h1, acc[1], 0, 0, 0);
            acc[1] = __builtin_amdgcn_mfma_f32_16x16x32_f16(a_h, b_l1, acc[1], 0, 0, 0);
        }
    };

    // ---- pipeline: double-buffered LDS, 1-chunk register prefetch, 1 barrier/chunk ----
    LOAD(0);
    STORE(0);
    LOAD(1);
    __syncthreads();

    for (int c = 0; c < NCH; ++c) {
        const int p = c & 1;
        COMPUTE(p);
        if (c + 1 < NCH) {
            STORE(p ^ 1);
            if (c + 2 < NCH) LOAD(c + 2);
        }
        __syncthreads();
    }

    // ---- epilogue: scale back (exact 2^-16) and top-2 per token ----
    const float sc = 1.0f / 65536.0f;
    #pragma unroll
    for (int n = 0; n < 2; ++n)
        #pragma unroll
        for (int r = 0; r < 4; ++r) {
            int tok = wm * 16 + (lane >> 4) * 4 + r;   // C/D: row=(lane>>4)*4+reg
            int e   = wn * 32 + n * 16 + (lane & 15);  //      col=lane&15 (m89)
            ss[tok][e] = acc[n][r] * sc;
        }
    __syncthreads();

    if (tid < MT) {
        const int t = tid;
        float m1 = -1e30f, m2 = -1e30f;
        int i1 = 0, i2 = 0;
        // strict '>' keeps the lower index on ties, matching jax.lax.top_k
        #pragma unroll
        for (int e = 0; e < NEXP; ++e) {
            float v = ss[t][e];
            if (v > m1) { m2 = m1; i2 = i1; m1 = v; i1 = e; }
            else if (v > m2) { m2 = v; i2 = e; }
        }
        const int gt = tb + t;
        out_w[gt * 2 + 0] = m1;
        out_w[gt * 2 + 1] = m2;
        out_i[gt * 2 + 0] = (float)i1;
        out_i[gt * 2 + 1] = (float)i2;
    }
}

extern "C" void kernel_launch(void* const* d_in, const int* in_sizes, int n_in,
                              void* d_out, int out_size, void* d_ws, size_t ws_size,
                              hipStream_t stream) {
    const float* x = (const float*)d_in[0];   // [16384, 2048] f32
    const float* W = (const float*)d_in[1];   // [64, 2048]   f32
    float* out = (float*)d_out;               // [16384*2 weights][16384*2 indices]

    const int n_tokens = in_sizes[0] / KDIM;  // 16384
    _Float16* Whp = (_Float16*)d_ws;          // 256 KB
    _Float16* Wlp = Whp + (size_t)NEXP * KDIM; // +256 KB

    hipLaunchKernelGGL(prep_w, dim3((NEXP * KDIM) / 256), dim3(256), 0, stream, W, Whp, Wlp);
    hipLaunchKernelGGL(router_kernel, dim3(n_tokens / MT), dim3(NTHR), 0, stream,
                       x, Whp, Wlp, out, out + 2 * (size_t)n_tokens);
}